// Round 6
// baseline (209.107 us; speedup 1.0000x reference)
//
#include <hip/hip_runtime.h>
#include <math.h>

// Problem constants
#define B_TOT 2048
#define S_LEN 256
#define DIN   3
#define H     128
#define DOUT  6
#define DT_C  0.1f

#define NROWS 4    // batch rows per block -> grid = 512 = 2 blocks/CU (independent barrier groups)
#define HPAD  136  // bf16 row stride in sh_h (128 + 8 pad), 272B, 16B-aligned rows
#define PPAD  136  // f32 row stride in sh_p

typedef __attribute__((ext_vector_type(8))) short short8;
typedef __attribute__((ext_vector_type(4))) float f32x4;
typedef __attribute__((ext_vector_type(2))) float f32x2;

__device__ __forceinline__ unsigned short f2bf(float f) {
  unsigned int u = __float_as_uint(f);
  u += 0x7FFFu + ((u >> 16) & 1u);          // round-to-nearest-even
  return (unsigned short)(u >> 16);
}
__device__ __forceinline__ float bf2f(unsigned short h) {
  return __uint_as_float(((unsigned int)h) << 16);
}

// One block = 4 batch rows, 256 threads (4 waves). Wave w owns j-tile [w*32, w*32+32)
// as two 16-wide m-tiles sharing B-fragments. 2 blocks/CU -> 2 waves/SIMD from
// INDEPENDENT barrier groups: one block's waves issue while the other stalls.
// Phase 1 (MFMA): preact[j][b] staged f32 to sh_p (valid b<4 lanes).
// Phase 2 (epilogue): thread owns 2 FIXED elems (b=tid>>6, j=(tid&63)*2 + 0..1);
//   h register-resident all 256 steps; tanh+integrate; bf16 h -> ping-pong sh_h.
__launch_bounds__(256, 2)
__global__ void ltc_kernel(const float* __restrict__ x,
                           const float* __restrict__ W_xh,
                           const float* __restrict__ W_hh,
                           const float* __restrict__ b_hh,
                           const float* __restrict__ log_tau,
                           const float* __restrict__ fc_W,
                           const float* __restrict__ fc_b,
                           float* __restrict__ out) {
  __shared__ alignas(16) unsigned short sh_h[2][16][HPAD];  // ping-pong h bf16; rows 4..15 stay 0
  __shared__ alignas(16) float sh_p[NROWS][PPAD];           // preact staging / final h fp32

  const int tid  = threadIdx.x;
  const int w    = tid >> 6;        // wave 0..3 -> j-tile [w*32, w*32+32)
  const int lane = tid & 63;
  const int quad = lane >> 4;       // 0..3
  const int l16  = lane & 15;       // b-column in B/D fragments
  const int rb0  = blockIdx.x * NROWS;

  // ---- zero both h buffers (rows 4..15 remain zero -> zero-padded B cols) ----
  {
    uint4* p = (uint4*)&sh_h[0][0][0];
    const int n16 = (2 * 16 * HPAD) / 8;  // shorts -> uint4 count
    for (int i = tid; i < n16; i += 256) p[i] = make_uint4(0, 0, 0, 0);
  }

  // ---- W_hh A-fragments (hi/lo split), register-resident all 256 steps ----
  // A[m=l16][k = kc*32 + quad*8 + i],  j = w*32 + t*16 + m
  short8 wa_hi[2][4], wa_lo[2][4];
#pragma unroll
  for (int t = 0; t < 2; ++t) {
    const int j = w * 32 + t * 16 + l16;
#pragma unroll
    for (int kc = 0; kc < 4; ++kc) {
      const float* src = W_hh + j * H + kc * 32 + quad * 8;
#pragma unroll
      for (int i = 0; i < 8; ++i) {
        float wv = src[i];
        unsigned short hi = f2bf(wv);
        unsigned short lo = f2bf(wv - bf2f(hi));
        wa_hi[t][kc][i] = (short)hi;
        wa_lo[t][kc][i] = (short)lo;
      }
    }
  }

  // ---- epilogue-thread mapping: 2 valid elems, fixed for all steps ----
  const int eb = tid >> 6;          // batch row 0..3 (== wave id)
  const int ej = (tid & 63) * 2;    // j base 0..126
  float ewx[2][3], ebh[2], ecc[2];
#pragma unroll
  for (int r = 0; r < 2; ++r) {
    const int j = ej + r;
    ewx[r][0] = W_xh[j * 3 + 0];
    ewx[r][1] = W_xh[j * 3 + 1];
    ewx[r][2] = W_xh[j * 3 + 2];
    ebh[r]    = b_hh[j];
    float lt  = log_tau[j];
    float tau = logf(1.f + expf(lt)) + 0.001f;   // softplus + eps, exact fp32, once
    ecc[r]    = DT_C / tau;
  }
  const float* xrow = x + (size_t)(rb0 + eb) * (S_LEN * DIN);

  float hreg[2] = {0.f, 0.f};  // fp32 h for (eb, ej..ej+1), register-resident

  // static LDS offsets
  const int rd_off  = l16 * HPAD + quad * 8;             // B-frag read base (+ kc*32)
  const int wrp_off = l16 * PPAD + w * 32 + quad * 4;    // preact store (valid lanes, + t*16)
  const int ep_off  = eb * PPAD + ej;                    // epilogue preact read (floats)
  const int eh_off  = eb * HPAD + ej;                    // epilogue h write (shorts)
  const bool pvalid = (l16 < NROWS);
  float* const shp = &sh_p[0][0];
  const unsigned short* __restrict__ buf0 = &sh_h[0][0][0];
  unsigned short* __restrict__ buf1 = &sh_h[1][0][0];

  __syncthreads();

  auto do_step = [&](const unsigned short* __restrict__ cur,
                     unsigned short* __restrict__ nxt, int s) {
    // issue x load for THIS step's epilogue early (hidden behind MFMA + barrier)
    float xc0 = xrow[s * 3 + 0];
    float xc1 = xrow[s * 3 + 1];
    float xc2 = xrow[s * 3 + 2];

    // B-fragments of h^T: B[k = kc*32+quad*8+i][n = l16] -- shared by both m-tiles
    short8 bf[4];
#pragma unroll
    for (int kc = 0; kc < 4; ++kc)
      bf[kc] = *(const short8*)(cur + rd_off + kc * 32);

    // 4 independent 4-deep MFMA chains (2 m-tiles x hi/lo)
    f32x4 acch[2] = {{0.f,0.f,0.f,0.f},{0.f,0.f,0.f,0.f}};
    f32x4 accl[2] = {{0.f,0.f,0.f,0.f},{0.f,0.f,0.f,0.f}};
#pragma unroll
    for (int kc = 0; kc < 4; ++kc) {
#pragma unroll
      for (int t = 0; t < 2; ++t) {
        acch[t] = __builtin_amdgcn_mfma_f32_16x16x32_bf16(wa_hi[t][kc], bf[kc], acch[t], 0, 0, 0);
        accl[t] = __builtin_amdgcn_mfma_f32_16x16x32_bf16(wa_lo[t][kc], bf[kc], accl[t], 0, 0, 0);
      }
    }

    // stage valid preact (b < 4) to LDS
    if (pvalid) {
#pragma unroll
      for (int t = 0; t < 2; ++t) {
        f32x4 v;
#pragma unroll
        for (int r = 0; r < 4; ++r) v[r] = acch[t][r] + accl[t][r];
        *(f32x4*)(shp + wrp_off + t * 16) = v;
      }
    }
    __syncthreads();

    // dense epilogue: 2 valid elems per thread
    f32x2 p = *(const f32x2*)(shp + ep_off);
#pragma unroll
    for (int r = 0; r < 2; ++r) {
      float pre = p[r] + ebh[r] + xc0 * ewx[r][0] + xc1 * ewx[r][1] + xc2 * ewx[r][2];
      float rc  = __builtin_amdgcn_rcpf(__expf(2.f * pre) + 1.f);
      float f   = 1.f - 2.f * rc;            // tanh, correct at +/-inf
      hreg[r] += ecc[r] * (f - hreg[r]);
    }
    unsigned int hv = (unsigned)f2bf(hreg[0]) | ((unsigned)f2bf(hreg[1]) << 16);
    *(unsigned int*)(nxt + eh_off) = hv;     // 4B store, row eb, cols ej..ej+1
    __syncthreads();
  };

  for (int s = 0; s < S_LEN; s += 2) {
    do_step(buf0, buf1, s);
    do_step(buf1, (unsigned short*)buf0, s + 1);
  }

  // ---- final head: params = softplus(h @ fc_W^T + fc_b), [4 x 6] per block ----
  {
    f32x2 v = {hreg[0], hreg[1]};
    *(f32x2*)(shp + ep_off) = v;             // full-precision h into sh_p
  }
  __syncthreads();

  if (tid < NROWS * DOUT) {
    const int b = tid / DOUT;
    const int o = tid - b * DOUT;
    const float* fw = fc_W + o * H;
    float acc = fc_b[o];
#pragma unroll 4
    for (int k = 0; k < H; ++k) acc += sh_p[b][k] * fw[k];
    float sp = (acc > 15.f) ? acc : logf(1.f + expf(acc));
    out[(rb0 + b) * DOUT + o] = sp;
  }
}

extern "C" void kernel_launch(void* const* d_in, const int* in_sizes, int n_in,
                              void* d_out, int out_size, void* d_ws, size_t ws_size,
                              hipStream_t stream) {
  const float* x       = (const float*)d_in[0];
  const float* W_xh    = (const float*)d_in[1];
  const float* W_hh    = (const float*)d_in[2];
  const float* b_hh    = (const float*)d_in[3];
  const float* log_tau = (const float*)d_in[4];
  const float* fc_W    = (const float*)d_in[5];
  const float* fc_b    = (const float*)d_in[6];
  float* out           = (float*)d_out;

  ltc_kernel<<<dim3(B_TOT / NROWS), dim3(256), 0, stream>>>(
      x, W_xh, W_hh, b_hh, log_tau, fc_W, fc_b, out);
}

// Round 7
// 180.195 us; speedup vs baseline: 1.1604x; 1.1604x over previous
//
#include <hip/hip_runtime.h>
#include <math.h>

// Problem constants
#define B_TOT 2048
#define S_LEN 256
#define DIN   3
#define H     128
#define DOUT  6
#define DT_C  0.1f

#define NROWS 8    // batch rows per block (valid cols of the n=16 MFMA face)
#define HPAD  136  // bf16 row stride in sh_h (128 + 8 pad)
#define PPAD  132  // f32 row stride in sh_p (head staging only)

typedef __attribute__((ext_vector_type(8))) short short8;
typedef __attribute__((ext_vector_type(4))) float f32x4;

__device__ __forceinline__ unsigned short f2bf(float f) {
  unsigned int u = __float_as_uint(f);
  u += 0x7FFFu + ((u >> 16) & 1u);          // round-to-nearest-even
  return (unsigned short)(u >> 16);
}
__device__ __forceinline__ float bf2f(unsigned short h) {
  return __uint_as_float(((unsigned int)h) << 16);
}
__device__ __forceinline__ float bperm(int srcLane, float v) {
  return __int_as_float(__builtin_amdgcn_ds_bpermute(srcLane << 2, __float_as_int(v)));
}

// One block = 8 batch rows, 512 threads (8 waves, 2/SIMD). Wave w owns j-tile
// [w*16, w*16+16) — BOTH for the MFMA (A = W_hh rows) and for the epilogue
// (its own D output), so D-frag -> epilogue-layout redistribution is intra-wave
// via ds_bpermute: no staging LDS round-trip, no extra barrier.
//   MFMA: D[m=j_loc][n=b] ; lane holds (b = lane&15, j_loc = quad*4 + r).
//   Epilogue: lane l owns (b = l&7, j = w*16 + 2*(l>>3) + {0,1}) — fully dense.
// B-frag LDS reads exec-masked to l16<8 (D cols n>=8 are discarded -> garbage OK).
// ONE barrier per step (h visibility); ping-pong h buffers, unroll x2.
__launch_bounds__(512, 2)
__global__ void ltc_kernel(const float* __restrict__ x,
                           const float* __restrict__ W_xh,
                           const float* __restrict__ W_hh,
                           const float* __restrict__ b_hh,
                           const float* __restrict__ log_tau,
                           const float* __restrict__ fc_W,
                           const float* __restrict__ fc_b,
                           float* __restrict__ out) {
  __shared__ alignas(16) unsigned short sh_h[2][NROWS][HPAD];  // ping-pong h bf16 (rows 0..7 only)
  __shared__ alignas(16) float sh_p[NROWS][PPAD];              // final h fp32 for head

  const int tid  = threadIdx.x;
  const int w    = tid >> 6;        // wave 0..7 -> j-tile [w*16, w*16+16)
  const int lane = tid & 63;
  const int quad = lane >> 4;       // 0..3
  const int l16  = lane & 15;       // b-column in B/D fragments
  const int rb0  = blockIdx.x * NROWS;

  // ---- zero both h buffers ----
  {
    uint4* p = (uint4*)&sh_h[0][0][0];
    const int n16 = (2 * NROWS * HPAD) / 8;  // shorts -> uint4 count
    for (int i = tid; i < n16; i += 512) p[i] = make_uint4(0, 0, 0, 0);
  }

  // ---- W_hh A-fragments (hi/lo split), register-resident all 256 steps ----
  // A[m=l16][k = kc*32 + quad*8 + i],  j = w*16 + m
  short8 wa_hi[4], wa_lo[4];
  {
    const int j = w * 16 + l16;
#pragma unroll
    for (int kc = 0; kc < 4; ++kc) {
      const float* src = W_hh + j * H + kc * 32 + quad * 8;
#pragma unroll
      for (int i = 0; i < 8; ++i) {
        float wv = src[i];
        unsigned short hi = f2bf(wv);
        unsigned short lo = f2bf(wv - bf2f(hi));
        wa_hi[kc][i] = (short)hi;
        wa_lo[kc][i] = (short)lo;
      }
    }
  }

  // ---- epilogue mapping: lane owns (b = lane&7, j = w*16 + 2*(lane>>3) + r) ----
  const int eb = lane & 7;
  const int ep = lane >> 3;               // 0..7
  const int ej = w * 16 + 2 * ep;
  float ewx[2][3], ebh[2], ecc[2];
#pragma unroll
  for (int r = 0; r < 2; ++r) {
    const int j = ej + r;
    ewx[r][0] = W_xh[j * 3 + 0];
    ewx[r][1] = W_xh[j * 3 + 1];
    ewx[r][2] = W_xh[j * 3 + 2];
    ebh[r]    = b_hh[j];
    float lt  = log_tau[j];
    float tau = logf(1.f + expf(lt)) + 0.001f;   // softplus + eps, exact fp32, once
    ecc[r]    = DT_C / tau;
  }
  const float* xrow = x + (size_t)(rb0 + eb) * (S_LEN * DIN);

  float hreg[2] = {0.f, 0.f};  // fp32 h for (eb, ej..ej+1), register-resident

  // redistribution source lane: (b=eb, j_loc=2*ep) held at lane (ep>>1)*16 + eb, reg 2*(ep&1)
  const int srcLane = ((ep >> 1) << 4) | eb;
  const bool odd    = (ep & 1) != 0;

  // static LDS offsets (shorts)
  const int rd_off = l16 * HPAD + quad * 8;     // B-frag read base (+ kc*32), l16<8 only
  const int wr_off = eb * HPAD + w * 16 + 2 * ep;
  const unsigned short* __restrict__ buf0 = &sh_h[0][0][0];
  unsigned short* __restrict__ buf1 = &sh_h[1][0][0];

  __syncthreads();

  auto do_step = [&](const unsigned short* __restrict__ cur,
                     unsigned short* __restrict__ nxt, int s) {
    // x for this step's epilogue (L1-warm after first pass; hidden behind MFMA)
    float xc0 = xrow[s * 3 + 0];
    float xc1 = xrow[s * 3 + 1];
    float xc2 = xrow[s * 3 + 2];

    // B-fragments of h^T, exec-masked to valid rows (cols n>=8 of D are discarded)
    short8 bf[4];
    if (l16 < NROWS) {
#pragma unroll
      for (int kc = 0; kc < 4; ++kc)
        bf[kc] = *(const short8*)(cur + rd_off + kc * 32);
    } else {
      short8 z = {0, 0, 0, 0, 0, 0, 0, 0};
#pragma unroll
      for (int kc = 0; kc < 4; ++kc) bf[kc] = z;
    }

    // two independent 4-deep MFMA chains (hi/lo W split)
    f32x4 ah = {0.f, 0.f, 0.f, 0.f};
    f32x4 al = {0.f, 0.f, 0.f, 0.f};
#pragma unroll
    for (int kc = 0; kc < 4; ++kc) {
      ah = __builtin_amdgcn_mfma_f32_16x16x32_bf16(wa_hi[kc], bf[kc], ah, 0, 0, 0);
      al = __builtin_amdgcn_mfma_f32_16x16x32_bf16(wa_lo[kc], bf[kc], al, 0, 0, 0);
    }
    float pre0 = ah[0] + al[0], pre1 = ah[1] + al[1];
    float pre2 = ah[2] + al[2], pre3 = ah[3] + al[3];

    // intra-wave redistribution D-frag -> epilogue layout (no LDS, no barrier)
    float e0a = bperm(srcLane, pre0), e0b = bperm(srcLane, pre2);
    float e1a = bperm(srcLane, pre1), e1b = bperm(srcLane, pre3);
    float p0 = odd ? e0b : e0a;
    float p1 = odd ? e1b : e1a;

    // dense epilogue: 2 elems/lane
    {
      float pr = p0 + ebh[0] + xc0 * ewx[0][0] + xc1 * ewx[0][1] + xc2 * ewx[0][2];
      float rc = __builtin_amdgcn_rcpf(__expf(2.f * pr) + 1.f);
      hreg[0] += ecc[0] * ((1.f - 2.f * rc) - hreg[0]);
    }
    {
      float pr = p1 + ebh[1] + xc0 * ewx[1][0] + xc1 * ewx[1][1] + xc2 * ewx[1][2];
      float rc = __builtin_amdgcn_rcpf(__expf(2.f * pr) + 1.f);
      hreg[1] += ecc[1] * ((1.f - 2.f * rc) - hreg[1]);
    }

    unsigned int hv = (unsigned)f2bf(hreg[0]) | ((unsigned)f2bf(hreg[1]) << 16);
    *(unsigned int*)(nxt + wr_off) = hv;     // 4B store, row eb, cols ej..ej+1
    __syncthreads();
  };

  for (int s = 0; s < S_LEN; s += 2) {
    do_step(buf0, buf1, s);
    do_step(buf1, (unsigned short*)buf0, s + 1);
  }

  // ---- final head: params = softplus(h @ fc_W^T + fc_b), [8 x 6] per block ----
  sh_p[eb][ej]     = hreg[0];
  sh_p[eb][ej + 1] = hreg[1];
  __syncthreads();

  if (tid < NROWS * DOUT) {
    const int b = tid / DOUT;
    const int o = tid - b * DOUT;
    const float* fw = fc_W + o * H;
    float acc = fc_b[o];
#pragma unroll 4
    for (int k = 0; k < H; ++k) acc += sh_p[b][k] * fw[k];
    float sp = (acc > 15.f) ? acc : logf(1.f + expf(acc));
    out[(rb0 + b) * DOUT + o] = sp;
  }
}

extern "C" void kernel_launch(void* const* d_in, const int* in_sizes, int n_in,
                              void* d_out, int out_size, void* d_ws, size_t ws_size,
                              hipStream_t stream) {
  const float* x       = (const float*)d_in[0];
  const float* W_xh    = (const float*)d_in[1];
  const float* W_hh    = (const float*)d_in[2];
  const float* b_hh    = (const float*)d_in[3];
  const float* log_tau = (const float*)d_in[4];
  const float* fc_W    = (const float*)d_in[5];
  const float* fc_b    = (const float*)d_in[6];
  float* out           = (float*)d_out;

  ltc_kernel<<<dim3(B_TOT / NROWS), dim3(512), 0, stream>>>(
      x, W_xh, W_hh, b_hh, log_tau, fc_W, fc_b, out);
}

// Round 8
// 162.903 us; speedup vs baseline: 1.2836x; 1.1061x over previous
//
#include <hip/hip_runtime.h>
#include <math.h>

// Problem constants
#define B_TOT 2048
#define S_LEN 256
#define DIN   3
#define H     128
#define DOUT  6
#define DT_C  0.1f

#define NROWS 8    // batch rows per block (valid cols of the n=16 MFMA face)
#define HPAD  136  // bf16 row stride in sh_h (128 + 8 pad)
#define PPAD  132  // f32 row stride in sh_p (head staging only)

// scale folded into W_hh/W_xh/b_hh so epilogue uses exp2 directly:
// tanh(p) = 1 - 2/(exp(2p)+1) = 1 - 2/(exp2(p * 2*log2e)+1)
#define PRESCALE 2.8853900817779268f   // 2*log2(e)

typedef __attribute__((ext_vector_type(8))) short short8;
typedef __attribute__((ext_vector_type(4))) float f32x4;

__device__ __forceinline__ unsigned short f2bf(float f) {
  unsigned int u = __float_as_uint(f);
  u += 0x7FFFu + ((u >> 16) & 1u);          // round-to-nearest-even
  return (unsigned short)(u >> 16);
}
__device__ __forceinline__ float bf2f(unsigned short h) {
  return __uint_as_float(((unsigned int)h) << 16);
}
// pack two f32 -> two bf16 (RNE) in one dword: ~6 VALU
__device__ __forceinline__ unsigned int pack2_bf16(float a, float b) {
  unsigned int ua = __float_as_uint(a), ub = __float_as_uint(b);
  ua = ua + 0x7FFFu + ((ua >> 16) & 1u);
  ub = ub + 0x7FFFu + ((ub >> 16) & 1u);
  return (ua >> 16) | (ub & 0xFFFF0000u);
}
__device__ __forceinline__ float bperm(int srcLane, float v) {
  return __int_as_float(__builtin_amdgcn_ds_bpermute(srcLane << 2, __float_as_int(v)));
}

// One block = 8 batch rows, 512 threads (8 waves, 2/SIMD). Wave w owns j-tile
// [w*16, w*16+16) for both MFMA (A = W_hh rows, PRESCALEd, hi/lo split) and the
// epilogue of its own D output; D-frag -> epilogue layout via intra-wave ds_bpermute.
//   MFMA: D[m=j_loc][n=b] ; lane holds (b = lane&15, j_loc = quad*4 + r).
//   Epilogue: lane l owns (b = l&7, j = w*16 + 2*(l>>3) + {0,1}) — fully dense.
// B-frag LDS reads exec-masked to l16<8; masked-out lanes keep their once-zeroed regs.
// ONE barrier per step; ping-pong h buffers; step pair shares vectorized x loads.
__launch_bounds__(512, 2)
__global__ void ltc_kernel(const float* __restrict__ x,
                           const float* __restrict__ W_xh,
                           const float* __restrict__ W_hh,
                           const float* __restrict__ b_hh,
                           const float* __restrict__ log_tau,
                           const float* __restrict__ fc_W,
                           const float* __restrict__ fc_b,
                           float* __restrict__ out) {
  __shared__ alignas(16) unsigned short sh_h[2][NROWS][HPAD];  // ping-pong h bf16
  __shared__ alignas(16) float sh_p[NROWS][PPAD];              // final h fp32 for head

  const int tid  = threadIdx.x;
  const int w    = tid >> 6;        // wave 0..7 -> j-tile [w*16, w*16+16)
  const int lane = tid & 63;
  const int quad = lane >> 4;       // 0..3
  const int l16  = lane & 15;       // b-column in B/D fragments
  const int rb0  = blockIdx.x * NROWS;

  // ---- zero both h buffers ----
  {
    uint4* p = (uint4*)&sh_h[0][0][0];
    const int n16 = (2 * NROWS * HPAD) / 8;  // shorts -> uint4 count
    for (int i = tid; i < n16; i += 512) p[i] = make_uint4(0, 0, 0, 0);
  }

  // ---- W_hh A-fragments (hi/lo split of PRESCALE*W), register-resident ----
  // A[m=l16][k = kc*32 + quad*8 + i],  j = w*16 + m
  short8 wa_hi[4], wa_lo[4];
  {
    const int j = w * 16 + l16;
#pragma unroll
    for (int kc = 0; kc < 4; ++kc) {
      const float* src = W_hh + j * H + kc * 32 + quad * 8;
#pragma unroll
      for (int i = 0; i < 8; ++i) {
        float wv = src[i] * PRESCALE;
        unsigned short hi = f2bf(wv);
        unsigned short lo = f2bf(wv - bf2f(hi));   // hi+lo == wv to ~fp32 precision
        wa_hi[kc][i] = (short)hi;
        wa_lo[kc][i] = (short)lo;
      }
    }
  }

  // ---- epilogue mapping: lane owns (b = lane&7, j = w*16 + 2*(lane>>3) + r) ----
  const int eb = lane & 7;
  const int ep = lane >> 3;               // 0..7
  const int ej = w * 16 + 2 * ep;
  float ewx[2][3], ebh[2], ecc[2], ea[2], encc2[2];
#pragma unroll
  for (int r = 0; r < 2; ++r) {
    const int j = ej + r;
    ewx[r][0] = W_xh[j * 3 + 0] * PRESCALE;
    ewx[r][1] = W_xh[j * 3 + 1] * PRESCALE;
    ewx[r][2] = W_xh[j * 3 + 2] * PRESCALE;
    ebh[r]    = b_hh[j] * PRESCALE;
    float lt  = log_tau[j];
    float tau = logf(1.f + expf(lt)) + 0.001f;   // softplus + eps, exact fp32, once
    float cc  = DT_C / tau;
    ecc[r]    = cc;
    ea[r]     = 1.f - cc;
    encc2[r]  = -2.f * cc;
  }
  const float* xp = x + (size_t)(rb0 + eb) * (S_LEN * DIN);

  float hreg[2] = {0.f, 0.f};  // fp32 h for (eb, ej..ej+1), register-resident

  // redistribution source lane: (b=eb, j_loc=2*ep) at lane (ep>>1)*16 + eb
  const int srcLane = ((ep >> 1) << 4) | eb;
  const bool odd    = (ep & 1) != 0;

  // static LDS offsets (shorts)
  const int rd_off = l16 * HPAD + quad * 8;     // B-frag read base (+ kc*32), l16<8 only
  const int wr_off = eb * HPAD + w * 16 + 2 * ep;
  const unsigned short* __restrict__ buf0 = &sh_h[0][0][0];
  unsigned short* __restrict__ buf1 = &sh_h[1][0][0];

  // persistent B-frag regs: zeroed ONCE; lanes l16>=8 never overwrite them
  short8 bf[4];
#pragma unroll
  for (int kc = 0; kc < 4; ++kc) bf[kc] = short8{0, 0, 0, 0, 0, 0, 0, 0};

  // x prefetch: 6 floats per 2-step pair as 3x float2 (8B-aligned: 24B stride)
  float2 pfa = *(const float2*)(xp);
  float2 pfb = *(const float2*)(xp + 2);
  float2 pfc = *(const float2*)(xp + 4);

  __syncthreads();

  auto do_step = [&](const unsigned short* __restrict__ cur,
                     unsigned short* __restrict__ nxt,
                     float xc0, float xc1, float xc2) {
    // x-projection term early (independent of LDS/MFMA)
    float t0 = __builtin_fmaf(xc2, ewx[0][2], ebh[0]);
    t0 = __builtin_fmaf(xc1, ewx[0][1], t0);
    t0 = __builtin_fmaf(xc0, ewx[0][0], t0);
    float t1 = __builtin_fmaf(xc2, ewx[1][2], ebh[1]);
    t1 = __builtin_fmaf(xc1, ewx[1][1], t1);
    t1 = __builtin_fmaf(xc0, ewx[1][0], t1);

    // B-fragments of h^T (masked; lanes >=8 keep zeros)
    if (l16 < NROWS) {
#pragma unroll
      for (int kc = 0; kc < 4; ++kc)
        bf[kc] = *(const short8*)(cur + rd_off + kc * 32);
    }

    // two independent 4-deep MFMA chains (hi/lo W split)
    f32x4 ah = {0.f, 0.f, 0.f, 0.f};
    f32x4 al = {0.f, 0.f, 0.f, 0.f};
#pragma unroll
    for (int kc = 0; kc < 4; ++kc) {
      ah = __builtin_amdgcn_mfma_f32_16x16x32_bf16(wa_hi[kc], bf[kc], ah, 0, 0, 0);
      al = __builtin_amdgcn_mfma_f32_16x16x32_bf16(wa_lo[kc], bf[kc], al, 0, 0, 0);
    }
    float pre0 = ah[0] + al[0], pre1 = ah[1] + al[1];
    float pre2 = ah[2] + al[2], pre3 = ah[3] + al[3];

    // intra-wave redistribution D-frag -> epilogue layout
    float e0a = bperm(srcLane, pre0), e0b = bperm(srcLane, pre2);
    float e1a = bperm(srcLane, pre1), e1b = bperm(srcLane, pre3);
    float p0 = odd ? e0b : e0a;
    float p1 = odd ? e1b : e1a;

    // epilogue (PRESCALEd): f = 1 - 2/(exp2(p+t)+1); h' = h*(1-cc) + cc*f
    {
      float e = __builtin_amdgcn_exp2f(p0 + t0);
      float rc = __builtin_amdgcn_rcpf(e + 1.f);
      hreg[0] = __builtin_fmaf(encc2[0], rc, __builtin_fmaf(hreg[0], ea[0], ecc[0]));
    }
    {
      float e = __builtin_amdgcn_exp2f(p1 + t1);
      float rc = __builtin_amdgcn_rcpf(e + 1.f);
      hreg[1] = __builtin_fmaf(encc2[1], rc, __builtin_fmaf(hreg[1], ea[1], ecc[1]));
    }

    *(unsigned int*)(nxt + wr_off) = pack2_bf16(hreg[0], hreg[1]);
    __syncthreads();
  };

  for (int s = 0; s < S_LEN; s += 2) {
    float2 xa = pfa, xb = pfb, xc = pfc;
    if (s + 2 < S_LEN) {           // uniform branch; prefetch next pair
      xp += 6;
      pfa = *(const float2*)(xp);
      pfb = *(const float2*)(xp + 2);
      pfc = *(const float2*)(xp + 4);
    }
    do_step(buf0, buf1, xa.x, xa.y, xb.x);
    do_step(buf1, (unsigned short*)buf0, xb.y, xc.x, xc.y);
  }

  // ---- final head: params = softplus(h @ fc_W^T + fc_b), [8 x 6] per block ----
  sh_p[eb][ej]     = hreg[0];
  sh_p[eb][ej + 1] = hreg[1];
  __syncthreads();

  if (tid < NROWS * DOUT) {
    const int b = tid / DOUT;
    const int o = tid - b * DOUT;
    const float* fw = fc_W + o * H;
    float acc = fc_b[o];
#pragma unroll 4
    for (int k = 0; k < H; ++k) acc += sh_p[b][k] * fw[k];
    float sp = (acc > 15.f) ? acc : logf(1.f + expf(acc));
    out[(rb0 + b) * DOUT + o] = sp;
  }
}

extern "C" void kernel_launch(void* const* d_in, const int* in_sizes, int n_in,
                              void* d_out, int out_size, void* d_ws, size_t ws_size,
                              hipStream_t stream) {
  const float* x       = (const float*)d_in[0];
  const float* W_xh    = (const float*)d_in[1];
  const float* W_hh    = (const float*)d_in[2];
  const float* b_hh    = (const float*)d_in[3];
  const float* log_tau = (const float*)d_in[4];
  const float* fc_W    = (const float*)d_in[5];
  const float* fc_b    = (const float*)d_in[6];
  float* out           = (float*)d_out;

  ltc_kernel<<<dim3(B_TOT / NROWS), dim3(512), 0, stream>>>(
      x, W_xh, W_hh, b_hh, log_tau, fc_W, fc_b, out);
}